// Round 1
// baseline (7241.717 us; speedup 1.0000x reference)
//
#include <hip/hip_runtime.h>
#include <hip/hip_bf16.h>

typedef float f32x4 __attribute__((ext_vector_type(4)));
typedef short s16x8 __attribute__((ext_vector_type(8)));

#define NV 1024
#define ND 1024
#define NJ 1024
#define NB 64
#define NU 512
#define NT 513            // U+1 steps
#define G3 3072           // 3*D
#define SLOT 65536        // NB*ND elements per h slot
#define NWG 64            // recurrence workgroups

static __device__ __forceinline__ float bf2f(unsigned short u) {
  union { unsigned int i; float f; } x; x.i = ((unsigned int)u) << 16; return x.f;
}
static __device__ __forceinline__ unsigned short f2bf(float f) {
  union { float f; unsigned int i; } x; x.f = f;
  unsigned int r = x.i + 0x7fffu + ((x.i >> 16) & 1u);   // RNE
  return (unsigned short)(r >> 16);
}

// Swizzled bf16 layout (K=1024 fixed -> 32 k-chunks of 32):
// element (r,k) lives at flat ((r>>4)*32 + (k>>5))*512 + ((r&15) | (((k>>3)&3)<<4))*8 + (k&7)
// This is exactly the mfma_f32_16x16x32_bf16 A/B fragment order: a wave's fragment
// load is 64 lanes x 16B contiguous.
static __device__ __forceinline__ void unswizzle(long e, int& r, int& k) {
  long blk = e >> 9; int l = (int)((e >> 3) & 63); int j = (int)(e & 7);
  r = (int)(blk >> 5) * 16 + (l & 15);
  k = ((int)(blk & 31)) * 32 + ((l >> 4) << 3) + j;
}

// One prep kernel: swizzle/convert all 4 weight matrices to bf16 fragment layout,
// bias_sum = bias_ih + bias_hh, fill h-slot 0 with initial_state, zero barrier flags.
__global__ void predictor_prep(const float* __restrict__ whh, const float* __restrict__ wih,
                               const float* __restrict__ em, const float* __restrict__ lw,
                               const float* __restrict__ bih, const float* __restrict__ bhh,
                               const float* __restrict__ init,
                               unsigned short* __restrict__ wh_sw, unsigned short* __restrict__ wi_sw,
                               unsigned short* __restrict__ em_sw, unsigned short* __restrict__ lw_sw,
                               float* __restrict__ bias_sum, unsigned short* __restrict__ hs,
                               unsigned int* __restrict__ flags) {
  long e = (long)blockIdx.x * 256 + threadIdx.x;
  const long nbig = 3145728, nsm = 1048576;
  if (e < nbig) { int r, k; unswizzle(e, r, k); wh_sw[e] = f2bf(whh[(long)r * 1024 + k]); return; }
  e -= nbig;
  if (e < nbig) { int r, k; unswizzle(e, r, k); wi_sw[e] = f2bf(wih[(long)r * 1024 + k]); return; }
  e -= nbig;
  if (e < nsm) { int r, k; unswizzle(e, r, k); em_sw[e] = f2bf(em[(long)r * 1024 + k]); return; }
  e -= nsm;
  if (e < nsm) { int r, k; unswizzle(e, r, k); lw_sw[e] = f2bf(lw[(long)r * 1024 + k]); return; }
  e -= nsm;
  if (e < 65536) { int r, k; unswizzle(e, r, k); hs[e] = f2bf(init[k]); return; }
  e -= 65536;
  if (e < 3072) { bias_sum[e] = bih[e] + bhh[e]; return; }
  e -= 3072;
  if (e < 64) flags[e] = 0u;
}

// Generic bf16 GEMM: out[row, nt*64 .. +64) = A_chunk @ B^T + bias. A and B are in
// swizzled fragment layout. Used for G_tab (chunk = 16 v-rows blocks) and the
// output projection (chunk = time slot; out row = b*513 + t).
__global__ __launch_bounds__(256) void predictor_gemm(
    const unsigned short* __restrict__ A, long a_chunk_stride,
    const unsigned short* __restrict__ Bw,
    const float* __restrict__ bias, float* __restrict__ out,
    int rowmul_i, int rowmul_c, int out_stride) {
  const int nt = blockIdx.x, chunk = blockIdx.y;
  const int tid = threadIdx.x, lane = tid & 63, wave = tid >> 6;
  const unsigned short* Ab = A + (long)chunk * a_chunk_stride + wave * 16384 + lane * 8;
  const unsigned short* Bb = Bw + (long)nt * 65536 + lane * 8;
  f32x4 a0 = {0,0,0,0}, a1 = {0,0,0,0}, a2 = {0,0,0,0}, a3 = {0,0,0,0};
#pragma unroll 4
  for (int kc = 0; kc < 32; ++kc) {
    s16x8 av = *(const s16x8*)(Ab + kc * 512);
    s16x8 w0 = *(const s16x8*)(Bb + kc * 512);
    s16x8 w1 = *(const s16x8*)(Bb + 16384 + kc * 512);
    s16x8 w2 = *(const s16x8*)(Bb + 32768 + kc * 512);
    s16x8 w3 = *(const s16x8*)(Bb + 49152 + kc * 512);
    a0 = __builtin_amdgcn_mfma_f32_16x16x32_bf16(av, w0, a0, 0, 0, 0);
    a1 = __builtin_amdgcn_mfma_f32_16x16x32_bf16(av, w1, a1, 0, 0, 0);
    a2 = __builtin_amdgcn_mfma_f32_16x16x32_bf16(av, w2, a2, 0, 0, 0);
    a3 = __builtin_amdgcn_mfma_f32_16x16x32_bf16(av, w3, a3, 0, 0, 0);
  }
  const int q = lane >> 4, nl = lane & 15, colbase = nt << 6;
#pragma unroll
  for (int j = 0; j < 4; ++j) {
    int il = (wave << 4) + (q << 2) + j;                 // local row 0..63
    long row = (long)il * rowmul_i + (long)chunk * rowmul_c;
    float* orow = out + row * out_stride + colbase;
    orow[nl]      = a0[j] + bias[colbase + nl];
    orow[16 + nl] = a1[j] + bias[colbase + 16 + nl];
    orow[32 + nl] = a2[j] + bias[colbase + 32 + nl];
    orow[48 + nl] = a3[j] + bias[colbase + 48 + nl];
  }
}

// Persistent recurrence: 64 WGs x 256 threads. WG wg owns d-slice [wg*16, wg*16+16)
// and the matching r/z/n rows of W_hh. r,z slices live in LDS for all 513 steps
// (64 KB static); the n slice streams from L2/L3. Grid barrier: per-WG monotone
// flag (release, agent scope); wave 0 polls all 64 flags (one lane each).
__global__ __launch_bounds__(256, 1) void predictor_rnn(
    const unsigned short* __restrict__ wh_sw, const float* __restrict__ gtab,
    const int* __restrict__ y, unsigned short* __restrict__ hs,
    unsigned int* __restrict__ flags) {
  __shared__ unsigned short Wrz[32768];   // 64 KB
  const int wg = blockIdx.x, tid = threadIdx.x, lane = tid & 63, wave = tid >> 6;
  {
    const s16x8* sr = (const s16x8*)(wh_sw + (long)wg * 16384);
    const s16x8* sz = (const s16x8*)(wh_sw + (long)(64 + wg) * 16384);
    s16x8* dr = (s16x8*)Wrz;
    s16x8* dz = (s16x8*)(Wrz + 16384);
    for (int i = tid; i < 2048; i += 256) { dr[i] = sr[i]; dz[i] = sz[i]; }
  }
  __syncthreads();
  const int q = lane >> 4, dloc = lane & 15, dg = (wg << 4) + dloc;
  const unsigned short* wn = wh_sw + (long)(128 + wg) * 16384 + lane * 8;
  const unsigned short* br_ = Wrz + lane * 8;
  const unsigned short* bz_ = Wrz + 16384 + lane * 8;
  // swizzled offset pieces for the (b, dg) scalar accesses
  const int kc_h = dg >> 5;
  const int lhi = ((dg >> 3) & 3) << 4;
  const int jk = dg & 7;
  const long hbase = (long)(wave * 32 + kc_h) * 512 + jk;

  for (int t = 1; t <= NT; ++t) {
    const unsigned short* hprev = hs + (long)(t - 1) * SLOT;
    unsigned short* hcur = hs + (long)t * SLOT;
    const unsigned short* ab = hprev + wave * 16384 + lane * 8;
    f32x4 ar = {0,0,0,0}, az = {0,0,0,0}, an = {0,0,0,0};
#pragma unroll 4
    for (int kc = 0; kc < 32; ++kc) {
      s16x8 av = *(const s16x8*)(ab + kc * 512);          // h fragment (global, coalesced 1KB/wave)
      s16x8 bn = *(const s16x8*)(wn + kc * 512);          // n-gate weights (global)
      s16x8 br = *(const s16x8*)(br_ + kc * 512);         // LDS
      s16x8 bz = *(const s16x8*)(bz_ + kc * 512);         // LDS
      ar = __builtin_amdgcn_mfma_f32_16x16x32_bf16(av, br, ar, 0, 0, 0);
      az = __builtin_amdgcn_mfma_f32_16x16x32_bf16(av, bz, az, 0, 0, 0);
      an = __builtin_amdgcn_mfma_f32_16x16x32_bf16(av, bn, an, 0, 0, 0);
    }
    // gate math: lane covers batches b = wave*16 + q*4 + j at column dg
#pragma unroll
    for (int j = 0; j < 4; ++j) {
      int bl = (q << 2) + j;                              // b & 15
      int b = (wave << 4) + bl;
      int tok = (t == 1) ? 0 : y[b * NU + (t - 2)];
      const float* g = gtab + (long)tok * G3 + dg;        // includes bias_ih + bias_hh
      float gr = g[0], gz = g[1024], gn = g[2048];
      long hoff = hbase + (long)(bl | lhi) * 8;
      float hold = bf2f(hprev[hoff]);
      float r = 1.f / (1.f + __expf(-(gr + ar[j])));
      float z = 1.f / (1.f + __expf(-(gz + az[j])));
      float np = gn + r * an[j];
      float e2 = __expf(-2.f * fabsf(np));                // overflow-safe tanh
      float tn = (1.f - e2) / (1.f + e2);
      tn = np < 0.f ? -tn : tn;
      hcur[hoff] = f2bf((1.f - z) * tn + z * hold);
    }
    __syncthreads();
    if (tid == 0)
      __hip_atomic_store(&flags[wg], (unsigned)t, __ATOMIC_RELEASE, __HIP_MEMORY_SCOPE_AGENT);
    if (wave == 0) {
      for (;;) {
        unsigned v = __hip_atomic_load(&flags[lane], __ATOMIC_RELAXED, __HIP_MEMORY_SCOPE_AGENT);
        if (__all((int)(v >= (unsigned)t))) break;
        __builtin_amdgcn_s_sleep(1);
      }
    }
    __syncthreads();
    __builtin_amdgcn_fence(__ATOMIC_ACQUIRE, "agent");    // make remote h slices visible
  }
}

extern "C" void kernel_launch(void* const* d_in, const int* in_sizes, int n_in,
                              void* d_out, int out_size, void* d_ws, size_t ws_size,
                              hipStream_t stream) {
  const int*   y    = (const int*)d_in[0];
  const float* em   = (const float*)d_in[1];
  const float* wih  = (const float*)d_in[2];
  const float* bih  = (const float*)d_in[3];
  const float* whh  = (const float*)d_in[4];
  const float* bhh  = (const float*)d_in[5];
  const float* lw   = (const float*)d_in[6];
  const float* lb   = (const float*)d_in[7];
  const float* init = (const float*)d_in[8];
  float* out = (float*)d_out;

  char* ws = (char*)d_ws;
  size_t off = 0;
  auto alloc = [&](size_t n) { void* p = ws + off; off += (n + 255) & ~(size_t)255; return p; };
  unsigned short* wh_sw   = (unsigned short*)alloc(6291456);    // W_hh bf16 swizzled
  unsigned short* wi_sw   = (unsigned short*)alloc(6291456);    // W_ih bf16 swizzled
  unsigned short* em_sw   = (unsigned short*)alloc(2097152);    // embed bf16 swizzled
  unsigned short* lw_sw   = (unsigned short*)alloc(2097152);    // linear_w bf16 swizzled
  float*          gtab    = (float*)alloc(12582912);            // [V,3072] token gate table
  float*          bias_sum= (float*)alloc(12288);               // bias_ih + bias_hh
  unsigned int*   flags   = (unsigned int*)alloc(256);          // grid barrier flags
  unsigned short* hs      = (unsigned short*)alloc(67371008UL); // 514 h slots, bf16 swizzled
  (void)ws_size; (void)in_sizes; (void)n_in; (void)out_size;

  // 1) convert/swizzle weights, build slot 0, zero flags
  predictor_prep<<<dim3(33037), dim3(256), 0, stream>>>(
      whh, wih, em, lw, bih, bhh, init, wh_sw, wi_sw, em_sw, lw_sw, bias_sum, hs, flags);
  // 2) G_tab[v] = embed[v] @ W_ih^T + (bias_ih + bias_hh)   (M=1024, N=3072, K=1024)
  predictor_gemm<<<dim3(48, 16), dim3(256), 0, stream>>>(
      em_sw, 65536L, wi_sw, bias_sum, gtab, /*rowmul_i=*/1, /*rowmul_c=*/64, /*stride=*/3072);
  // 3) 513 GRU steps, persistent cooperative kernel
  predictor_rnn<<<dim3(NWG), dim3(256), 0, stream>>>(wh_sw, gtab, y, hs, flags);
  // 4) out[b,u,:] = hs[u+1][b] @ linear_w^T + linear_b  (chunk = u, row = b*513 + u)
  predictor_gemm<<<dim3(16, 513), dim3(256), 0, stream>>>(
      hs + 65536, 65536L, lw_sw, lb, out, /*rowmul_i=*/513, /*rowmul_c=*/1, /*stride=*/1024);
}

// Round 2
// 5226.414 us; speedup vs baseline: 1.3856x; 1.3856x over previous
//
#include <hip/hip_runtime.h>
#include <hip/hip_bf16.h>

typedef float f32x4 __attribute__((ext_vector_type(4)));
typedef short s16x8 __attribute__((ext_vector_type(8)));
typedef int   i32x4 __attribute__((ext_vector_type(4)));

#define NV 1024
#define ND 1024
#define NJ 1024
#define NB 64
#define NU 512
#define NT 513            // U+1 steps
#define G3 3072           // 3*D
#define SLOT 65536        // NB*ND elements per h slot
#define NWG 64            // recurrence workgroups

static __device__ __forceinline__ float bf2f(unsigned short u) {
  union { unsigned int i; float f; } x; x.i = ((unsigned int)u) << 16; return x.f;
}
static __device__ __forceinline__ unsigned short f2bf(float f) {
  union { float f; unsigned int i; } x; x.f = f;
  unsigned int r = x.i + 0x7fffu + ((x.i >> 16) & 1u);   // RNE
  return (unsigned short)(r >> 16);
}

// Swizzled bf16 layout (K=1024 fixed -> 32 k-chunks of 32):
// element (r,k) -> flat ((r>>4)*32 + (k>>5))*512 + ((r&15) | (((k>>3)&3)<<4))*8 + (k&7)
// = exact mfma_f32_16x16x32_bf16 A/B fragment order (64 lanes x 16B contiguous).
static __device__ __forceinline__ void unswizzle(long e, int& r, int& k) {
  long blk = e >> 9; int l = (int)((e >> 3) & 63); int j = (int)(e & 7);
  r = (int)(blk >> 5) * 16 + (l & 15);
  k = ((int)(blk & 31)) * 32 + ((l >> 4) << 3) + j;
}

__global__ void predictor_prep(const float* __restrict__ whh, const float* __restrict__ wih,
                               const float* __restrict__ em, const float* __restrict__ lw,
                               const float* __restrict__ bih, const float* __restrict__ bhh,
                               const float* __restrict__ init,
                               unsigned short* __restrict__ wh_sw, unsigned short* __restrict__ wi_sw,
                               unsigned short* __restrict__ em_sw, unsigned short* __restrict__ lw_sw,
                               float* __restrict__ bias_sum, unsigned short* __restrict__ hs,
                               unsigned int* __restrict__ flags) {
  long e = (long)blockIdx.x * 256 + threadIdx.x;
  const long nbig = 3145728, nsm = 1048576;
  if (e < nbig) { int r, k; unswizzle(e, r, k); wh_sw[e] = f2bf(whh[(long)r * 1024 + k]); return; }
  e -= nbig;
  if (e < nbig) { int r, k; unswizzle(e, r, k); wi_sw[e] = f2bf(wih[(long)r * 1024 + k]); return; }
  e -= nbig;
  if (e < nsm) { int r, k; unswizzle(e, r, k); em_sw[e] = f2bf(em[(long)r * 1024 + k]); return; }
  e -= nsm;
  if (e < nsm) { int r, k; unswizzle(e, r, k); lw_sw[e] = f2bf(lw[(long)r * 1024 + k]); return; }
  e -= nsm;
  if (e < 65536) { int r, k; unswizzle(e, r, k); hs[e] = f2bf(init[k]); return; }
  e -= 65536;
  if (e < 3072) { bias_sum[e] = bih[e] + bhh[e]; return; }
  e -= 3072;
  if (e < 256) flags[e] = 0u;
}

// Generic bf16 GEMM (unchanged from R1): out[row, nt*64 .. +64) = A_chunk @ B^T + bias.
__global__ __launch_bounds__(256) void predictor_gemm(
    const unsigned short* __restrict__ A, long a_chunk_stride,
    const unsigned short* __restrict__ Bw,
    const float* __restrict__ bias, float* __restrict__ out,
    int rowmul_i, int rowmul_c, int out_stride) {
  const int nt = blockIdx.x, chunk = blockIdx.y;
  const int tid = threadIdx.x, lane = tid & 63, wave = tid >> 6;
  const unsigned short* Ab = A + (long)chunk * a_chunk_stride + wave * 16384 + lane * 8;
  const unsigned short* Bb = Bw + (long)nt * 65536 + lane * 8;
  f32x4 a0 = {0,0,0,0}, a1 = {0,0,0,0}, a2 = {0,0,0,0}, a3 = {0,0,0,0};
#pragma unroll 4
  for (int kc = 0; kc < 32; ++kc) {
    s16x8 av = *(const s16x8*)(Ab + kc * 512);
    s16x8 w0 = *(const s16x8*)(Bb + kc * 512);
    s16x8 w1 = *(const s16x8*)(Bb + 16384 + kc * 512);
    s16x8 w2 = *(const s16x8*)(Bb + 32768 + kc * 512);
    s16x8 w3 = *(const s16x8*)(Bb + 49152 + kc * 512);
    a0 = __builtin_amdgcn_mfma_f32_16x16x32_bf16(av, w0, a0, 0, 0, 0);
    a1 = __builtin_amdgcn_mfma_f32_16x16x32_bf16(av, w1, a1, 0, 0, 0);
    a2 = __builtin_amdgcn_mfma_f32_16x16x32_bf16(av, w2, a2, 0, 0, 0);
    a3 = __builtin_amdgcn_mfma_f32_16x16x32_bf16(av, w3, a3, 0, 0, 0);
  }
  const int q = lane >> 4, nl = lane & 15, colbase = nt << 6;
#pragma unroll
  for (int j = 0; j < 4; ++j) {
    int il = (wave << 4) + (q << 2) + j;
    long row = (long)il * rowmul_i + (long)chunk * rowmul_c;
    float* orow = out + row * out_stride + colbase;
    orow[nl]      = a0[j] + bias[colbase + nl];
    orow[16 + nl] = a1[j] + bias[colbase + 16 + nl];
    orow[32 + nl] = a2[j] + bias[colbase + 32 + nl];
    orow[48 + nl] = a3[j] + bias[colbase + 48 + nl];
  }
}

// Persistent recurrence v2: 64 WGs x 256 threads, WG wg owns d-slice [wg*16,+16).
// Waves K-split (wave w -> k-chunks [w*8, w*8+8)); weights for all 3 gates live in
// REGISTERS (24 fragments); cross-wave K-reduction via 48 KB LDS + 1 syncthreads.
// Cross-WG h exchange & flags use sc1 (device-coherent) accesses -> NO L2 wb/inv.
__global__ __launch_bounds__(256, 1) void predictor_rnn(
    const unsigned short* __restrict__ wh_sw, const float* __restrict__ gtab,
    const int* __restrict__ y, const float* __restrict__ init,
    unsigned short* __restrict__ hs, unsigned int* __restrict__ flags) {
  __shared__ float buf[4][3][4][64][4];   // [writer_wave][gate][bgroup][lane][4] = 48 KB
  const int wg = blockIdx.x, tid = threadIdx.x, lane = tid & 63, w = tid >> 6;
  const int q = lane >> 4, dloc = lane & 15, dg = (wg << 4) + dloc;

  // Weight fragments -> registers (loop-invariant, cached reads).
  s16x8 wr[8], wz[8], wn[8];
#pragma unroll
  for (int i = 0; i < 8; ++i) {
    int kc = (w << 3) + i;
    wr[i] = *(const s16x8*)(wh_sw + ((long)(      wg) << 14) + kc * 512 + lane * 8);
    wz[i] = *(const s16x8*)(wh_sw + ((long)( 64 + wg) << 14) + kc * 512 + lane * 8);
    wn[i] = *(const s16x8*)(wh_sw + ((long)(128 + wg) << 14) + kc * 512 + lane * 8);
  }
  float hreg[4];
#pragma unroll
  for (int j = 0; j < 4; ++j) hreg[j] = init[dg];

  // swizzled offset pieces for the h store of (b, dg)
  const int kc_h = dg >> 5, lhi = ((dg >> 3) & 3) << 4, jk = dg & 7;
  const long hbase = (long)(w * 32 + kc_h) * 512 + jk;
  const unsigned int* fp = flags + lane * 4;

  for (int t = 1; t <= NT; ++t) {
    if (t > 1) {
      const unsigned int tm1 = (unsigned)(t - 1);
      for (;;) {
        i32x4 fv;
        asm volatile("global_load_dwordx4 %0, %1, off sc1" : "=v"(fv) : "v"(fp) : "memory");
        asm volatile("s_waitcnt vmcnt(0)" : "+v"(fv) :: "memory");
        int ok = ((unsigned)fv.x >= tm1) & ((unsigned)fv.y >= tm1) &
                 ((unsigned)fv.z >= tm1) & ((unsigned)fv.w >= tm1);
        if (__all(ok)) break;
        __builtin_amdgcn_s_sleep(1);
      }
    }
    const unsigned short* hprev = hs + (long)(t - 1) * SLOT;
    unsigned short* hcur = hs + (long)t * SLOT;

    // Issue all 32 A-fragment loads (sc1: coherent, bypasses stale L2), one drain.
    s16x8 hf[32];
#pragma unroll
    for (int bg = 0; bg < 4; ++bg)
#pragma unroll
      for (int i = 0; i < 8; ++i) {
        const unsigned short* a = hprev + bg * 16384 + ((w << 3) + i) * 512 + lane * 8;
        asm volatile("global_load_dwordx4 %0, %1, off sc1" : "=v"(hf[bg * 8 + i]) : "v"(a) : "memory");
      }
    asm volatile("s_waitcnt vmcnt(0)" ::: "memory");
#pragma unroll
    for (int x = 0; x < 32; ++x) asm volatile("" : "+v"(hf[x]));   // pin uses after waitcnt

    f32x4 aR[4], aZ[4], aN[4];
#pragma unroll
    for (int bg = 0; bg < 4; ++bg) { aR[bg] = (f32x4){0,0,0,0}; aZ[bg] = (f32x4){0,0,0,0}; aN[bg] = (f32x4){0,0,0,0}; }
#pragma unroll
    for (int i = 0; i < 8; ++i)
#pragma unroll
      for (int bg = 0; bg < 4; ++bg) {
        aR[bg] = __builtin_amdgcn_mfma_f32_16x16x32_bf16(hf[bg * 8 + i], wr[i], aR[bg], 0, 0, 0);
        aZ[bg] = __builtin_amdgcn_mfma_f32_16x16x32_bf16(hf[bg * 8 + i], wz[i], aZ[bg], 0, 0, 0);
        aN[bg] = __builtin_amdgcn_mfma_f32_16x16x32_bf16(hf[bg * 8 + i], wn[i], aN[bg], 0, 0, 0);
      }

    // K-reduction exchange: write partials for bgroups we don't own.
#pragma unroll
    for (int b2 = 0; b2 < 4; ++b2)
      if (b2 != w) {
        *(f32x4*)&buf[w][0][b2][lane][0] = aR[b2];
        *(f32x4*)&buf[w][1][b2][lane][0] = aZ[b2];
        *(f32x4*)&buf[w][2][b2][lane][0] = aN[b2];
      }
    __syncthreads();
    f32x4 sR = aR[w], sZ = aZ[w], sN = aN[w];
#pragma unroll
    for (int v = 0; v < 4; ++v)
      if (v != w) {
        sR += *(const f32x4*)&buf[v][0][w][lane][0];
        sZ += *(const f32x4*)&buf[v][1][w][lane][0];
        sN += *(const f32x4*)&buf[v][2][w][lane][0];
      }

    // Gate epilogue for our 16 batches; fp32 h chain lives in hreg[].
#pragma unroll
    for (int j = 0; j < 4; ++j) {
      int bl = (q << 2) + j;
      int b = (w << 4) + bl;
      int tok = (t == 1) ? 0 : y[b * NU + (t - 2)];
      const float* g = gtab + (long)tok * G3 + dg;      // bias_ih + bias_hh folded in
      float r = 1.f / (1.f + __expf(-(g[0] + sR[j])));
      float z = 1.f / (1.f + __expf(-(g[1024] + sZ[j])));
      float np = g[2048] + r * sN[j];
      float e2 = __expf(-2.f * fabsf(np));              // overflow-safe tanh
      float tn = (1.f - e2) / (1.f + e2);
      tn = np < 0.f ? -tn : tn;
      float hnew = (1.f - z) * tn + z * hreg[j];
      hreg[j] = hnew;
      const unsigned short* sa = hcur + hbase + (long)(bl | lhi) * 8;
      asm volatile("global_store_short %0, %1, off sc1" :: "v"(sa), "v"((unsigned)f2bf(hnew)) : "memory");
    }
    asm volatile("s_waitcnt vmcnt(0)" ::: "memory");     // h stores at coherence point
    if (lane == 0)
      __hip_atomic_store(&flags[(wg << 2) | w], (unsigned)t, __ATOMIC_RELAXED, __HIP_MEMORY_SCOPE_AGENT);
  }
}

extern "C" void kernel_launch(void* const* d_in, const int* in_sizes, int n_in,
                              void* d_out, int out_size, void* d_ws, size_t ws_size,
                              hipStream_t stream) {
  const int*   y    = (const int*)d_in[0];
  const float* em   = (const float*)d_in[1];
  const float* wih  = (const float*)d_in[2];
  const float* bih  = (const float*)d_in[3];
  const float* whh  = (const float*)d_in[4];
  const float* bhh  = (const float*)d_in[5];
  const float* lw   = (const float*)d_in[6];
  const float* lb   = (const float*)d_in[7];
  const float* init = (const float*)d_in[8];
  float* out = (float*)d_out;

  char* ws = (char*)d_ws;
  size_t off = 0;
  auto alloc = [&](size_t n) { void* p = ws + off; off += (n + 255) & ~(size_t)255; return p; };
  unsigned short* wh_sw   = (unsigned short*)alloc(6291456);    // W_hh bf16 swizzled
  unsigned short* wi_sw   = (unsigned short*)alloc(6291456);    // W_ih bf16 swizzled
  unsigned short* em_sw   = (unsigned short*)alloc(2097152);    // embed bf16 swizzled
  unsigned short* lw_sw   = (unsigned short*)alloc(2097152);    // linear_w bf16 swizzled
  float*          gtab    = (float*)alloc(12582912);            // [V,3072] token gate table
  float*          bias_sum= (float*)alloc(12288);               // bias_ih + bias_hh
  unsigned int*   flags   = (unsigned int*)alloc(1024);         // 256 per-wave flags
  unsigned short* hs      = (unsigned short*)alloc(67371008UL); // 514 h slots, bf16 swizzled
  (void)ws_size; (void)in_sizes; (void)n_in; (void)out_size;

  predictor_prep<<<dim3(33037), dim3(256), 0, stream>>>(
      whh, wih, em, lw, bih, bhh, init, wh_sw, wi_sw, em_sw, lw_sw, bias_sum, hs, flags);
  predictor_gemm<<<dim3(48, 16), dim3(256), 0, stream>>>(
      em_sw, 65536L, wi_sw, bias_sum, gtab, /*rowmul_i=*/1, /*rowmul_c=*/64, /*stride=*/3072);
  predictor_rnn<<<dim3(NWG), dim3(256), 0, stream>>>(wh_sw, gtab, y, init, hs, flags);
  predictor_gemm<<<dim3(16, 513), dim3(256), 0, stream>>>(
      hs + 65536, 65536L, lw_sw, lb, out, /*rowmul_i=*/513, /*rowmul_c=*/1, /*stride=*/1024);
}

// Round 3
// 3310.946 us; speedup vs baseline: 2.1872x; 1.5785x over previous
//
#include <hip/hip_runtime.h>
#include <hip/hip_bf16.h>

typedef float f32x4 __attribute__((ext_vector_type(4)));
typedef short s16x8 __attribute__((ext_vector_type(8)));
typedef int   i32x4 __attribute__((ext_vector_type(4)));
typedef _Float16 h16x8 __attribute__((ext_vector_type(8)));

#define NV 1024
#define ND 1024
#define NJ 1024
#define NB 64
#define NU 512
#define NT 513            // U+1 steps
#define G3 3072           // 3*D
#define SLOT 65536        // NB*ND elements per h slot
#define NWG 64            // recurrence workgroups
#define FSTRIDE 32        // flags spread: one per 128-B line

static __device__ __forceinline__ unsigned short f2h(float f) {
  union { _Float16 h; unsigned short u; } x; x.h = (_Float16)f;   // RNE
  return x.u;
}

// Swizzled fp16 layout (K=1024 -> 32 k-chunks of 32):
// element (r,k) -> flat ((r>>4)*32 + (k>>5))*512 + ((r&15) | (((k>>3)&3)<<4))*8 + (k&7)
// = exact mfma_f32_16x16x32_f16 A/B fragment order (64 lanes x 16B contiguous).
static __device__ __forceinline__ void unswizzle(long e, int& r, int& k) {
  long blk = e >> 9; int l = (int)((e >> 3) & 63); int j = (int)(e & 7);
  r = (int)(blk >> 5) * 16 + (l & 15);
  k = ((int)(blk & 31)) * 32 + ((l >> 4) << 3) + j;
}

__global__ void predictor_prep(const float* __restrict__ whh, const float* __restrict__ wih,
                               const float* __restrict__ em, const float* __restrict__ lw,
                               const float* __restrict__ bih, const float* __restrict__ bhh,
                               const float* __restrict__ init,
                               unsigned short* __restrict__ wh_sw, unsigned short* __restrict__ wi_sw,
                               unsigned short* __restrict__ em_sw, unsigned short* __restrict__ lw_sw,
                               float* __restrict__ bias_sum, unsigned short* __restrict__ hs,
                               unsigned int* __restrict__ flags) {
  long e = (long)blockIdx.x * 256 + threadIdx.x;
  const long nbig = 3145728, nsm = 1048576;
  if (e < nbig) { int r, k; unswizzle(e, r, k); wh_sw[e] = f2h(whh[(long)r * 1024 + k]); return; }
  e -= nbig;
  if (e < nbig) { int r, k; unswizzle(e, r, k); wi_sw[e] = f2h(wih[(long)r * 1024 + k]); return; }
  e -= nbig;
  if (e < nsm) { int r, k; unswizzle(e, r, k); em_sw[e] = f2h(em[(long)r * 1024 + k]); return; }
  e -= nsm;
  if (e < nsm) { int r, k; unswizzle(e, r, k); lw_sw[e] = f2h(lw[(long)r * 1024 + k]); return; }
  e -= nsm;
  if (e < 65536) { int r, k; unswizzle(e, r, k); hs[e] = f2h(init[k]); return; }
  e -= 65536;
  if (e < 3072) { bias_sum[e] = bih[e] + bhh[e]; return; }
  e -= 3072;
  if (e < 2048) flags[e] = 0u;
}

// Generic fp16 GEMM: out[row, nt*64 .. +64) = A_chunk @ B^T + bias (fragment layouts).
__global__ __launch_bounds__(256) void predictor_gemm(
    const unsigned short* __restrict__ A, long a_chunk_stride,
    const unsigned short* __restrict__ Bw,
    const float* __restrict__ bias, float* __restrict__ out,
    int rowmul_i, int rowmul_c, int out_stride) {
  const int nt = blockIdx.x, chunk = blockIdx.y;
  const int tid = threadIdx.x, lane = tid & 63, wave = tid >> 6;
  const unsigned short* Ab = A + (long)chunk * a_chunk_stride + wave * 16384 + lane * 8;
  const unsigned short* Bb = Bw + (long)nt * 65536 + lane * 8;
  f32x4 a0 = {0,0,0,0}, a1 = {0,0,0,0}, a2 = {0,0,0,0}, a3 = {0,0,0,0};
#pragma unroll 4
  for (int kc = 0; kc < 32; ++kc) {
    h16x8 av = __builtin_bit_cast(h16x8, *(const s16x8*)(Ab + kc * 512));
    h16x8 w0 = __builtin_bit_cast(h16x8, *(const s16x8*)(Bb + kc * 512));
    h16x8 w1 = __builtin_bit_cast(h16x8, *(const s16x8*)(Bb + 16384 + kc * 512));
    h16x8 w2 = __builtin_bit_cast(h16x8, *(const s16x8*)(Bb + 32768 + kc * 512));
    h16x8 w3 = __builtin_bit_cast(h16x8, *(const s16x8*)(Bb + 49152 + kc * 512));
    a0 = __builtin_amdgcn_mfma_f32_16x16x32_f16(av, w0, a0, 0, 0, 0);
    a1 = __builtin_amdgcn_mfma_f32_16x16x32_f16(av, w1, a1, 0, 0, 0);
    a2 = __builtin_amdgcn_mfma_f32_16x16x32_f16(av, w2, a2, 0, 0, 0);
    a3 = __builtin_amdgcn_mfma_f32_16x16x32_f16(av, w3, a3, 0, 0, 0);
  }
  const int q = lane >> 4, nl = lane & 15, colbase = nt << 6;
#pragma unroll
  for (int j = 0; j < 4; ++j) {
    int il = (wave << 4) + (q << 2) + j;
    long row = (long)il * rowmul_i + (long)chunk * rowmul_c;
    float* orow = out + row * out_stride + colbase;
    orow[nl]      = a0[j] + bias[colbase + nl];
    orow[16 + nl] = a1[j] + bias[colbase + 16 + nl];
    orow[32 + nl] = a2[j] + bias[colbase + 32 + nl];
    orow[48 + nl] = a3[j] + bias[colbase + 48 + nl];
  }
}

#define PINSTAGE(CNT, B)                                                        \
  asm volatile("s_waitcnt vmcnt(" #CNT ")"                                      \
    : "+v"(hf[(B)*8+0]), "+v"(hf[(B)*8+1]), "+v"(hf[(B)*8+2]), "+v"(hf[(B)*8+3]), \
      "+v"(hf[(B)*8+4]), "+v"(hf[(B)*8+5]), "+v"(hf[(B)*8+6]), "+v"(hf[(B)*8+7]) :: "memory")

// Persistent recurrence v3: 64 WGs x 256 threads, WG wg owns d-slice [wg*16,+16).
// Wave w K-splits (k-chunks [w*8,w*8+8)); all weight fragments in registers.
// Barrier: one spread flag per WG (128-B apart); only wave 0 polls. h stores are
// coalesced dwordx2 via a 2 KB LDS transpose (full-line writes). h loads staged
// vmcnt(24/16/8/0) so MFMA overlaps the load tail. gtab/y prefetched pre-poll.
__global__ __launch_bounds__(256, 1) void predictor_rnn(
    const unsigned short* __restrict__ wh_sw, const float* __restrict__ gtab,
    const int* __restrict__ y, const float* __restrict__ init,
    unsigned short* __restrict__ hs, unsigned int* __restrict__ flags) {
  __shared__ float buf[4][3][4][64][4];   // K-reduction exchange, 48 KB
  __shared__ unsigned short tbuf[1024];   // h store transpose, 2 KB
  const int wg = blockIdx.x, tid = threadIdx.x, lane = tid & 63, w = tid >> 6;
  const int q = lane >> 4, dloc = lane & 15, dg = (wg << 4) + dloc;

  // Weight fragments -> registers (loop-invariant cached reads).
  h16x8 wrf[8], wzf[8], wnf[8];
#pragma unroll
  for (int i = 0; i < 8; ++i) {
    int kc = (w << 3) + i;
    wrf[i] = __builtin_bit_cast(h16x8, *(const s16x8*)(wh_sw + ((long)(      wg) << 14) + kc * 512 + lane * 8));
    wzf[i] = __builtin_bit_cast(h16x8, *(const s16x8*)(wh_sw + ((long)( 64 + wg) << 14) + kc * 512 + lane * 8));
    wnf[i] = __builtin_bit_cast(h16x8, *(const s16x8*)(wh_sw + ((long)(128 + wg) << 14) + kc * 512 + lane * 8));
  }
  float hreg[4];
#pragma unroll
  for (int j = 0; j < 4; ++j) hreg[j] = init[dg];

  for (int t = 1; t <= NT; ++t) {
    // ---- prefetch gate table rows (independent of the barrier) ----
    float gr[4], gz[4], gn[4];
#pragma unroll
    for (int j = 0; j < 4; ++j) {
      int b = (w << 4) + (q << 2) + j;
      int tok = (t == 1) ? 0 : y[b * NU + (t - 2)];
      const float* g = gtab + (long)tok * G3 + dg;
      asm volatile("global_load_dword %0, %1, off" : "=v"(gr[j]) : "v"(g) : "memory");
      asm volatile("global_load_dword %0, %1, off" : "=v"(gz[j]) : "v"(g + 1024) : "memory");
      asm volatile("global_load_dword %0, %1, off" : "=v"(gn[j]) : "v"(g + 2048) : "memory");
    }
    asm volatile("s_waitcnt vmcnt(0)"
      : "+v"(gr[0]), "+v"(gr[1]), "+v"(gr[2]), "+v"(gr[3]),
        "+v"(gz[0]), "+v"(gz[1]), "+v"(gz[2]), "+v"(gz[3]),
        "+v"(gn[0]), "+v"(gn[1]), "+v"(gn[2]), "+v"(gn[3]) :: "memory");

    // ---- barrier wait: only wave 0 polls, one flag line per WG ----
    if (w == 0 && t > 1) {
      const unsigned int* fp = flags + lane * FSTRIDE;
      const unsigned int tm1 = (unsigned)(t - 1);
      for (;;) {
        unsigned int v;
        asm volatile("global_load_dword %0, %1, off sc1" : "=v"(v) : "v"(fp) : "memory");
        asm volatile("s_waitcnt vmcnt(0)" : "+v"(v) :: "memory");
        if (__all((int)(v >= tm1))) break;
        __builtin_amdgcn_s_sleep(2);
      }
    }
    __syncthreads();

    const unsigned short* hprev = hs + (long)(t - 1) * SLOT;
    unsigned short* hcur = hs + (long)t * SLOT;

    // ---- issue all 32 coherent h-fragment loads, consume in 4 staged groups ----
    i32x4 hf[32];
#pragma unroll
    for (int bg = 0; bg < 4; ++bg)
#pragma unroll
      for (int i = 0; i < 8; ++i) {
        const unsigned short* a = hprev + bg * 16384 + ((w << 3) + i) * 512 + lane * 8;
        asm volatile("global_load_dwordx4 %0, %1, off sc1" : "=v"(hf[bg * 8 + i]) : "v"(a) : "memory");
      }
    f32x4 aR[4], aZ[4], aN[4];
#pragma unroll
    for (int bg = 0; bg < 4; ++bg) { aR[bg] = (f32x4){0,0,0,0}; aZ[bg] = (f32x4){0,0,0,0}; aN[bg] = (f32x4){0,0,0,0}; }
    {
      PINSTAGE(24, 0);
#pragma unroll
      for (int i = 0; i < 8; ++i) { h16x8 a = __builtin_bit_cast(h16x8, hf[0 * 8 + i]);
        aR[0] = __builtin_amdgcn_mfma_f32_16x16x32_f16(a, wrf[i], aR[0], 0, 0, 0);
        aZ[0] = __builtin_amdgcn_mfma_f32_16x16x32_f16(a, wzf[i], aZ[0], 0, 0, 0);
        aN[0] = __builtin_amdgcn_mfma_f32_16x16x32_f16(a, wnf[i], aN[0], 0, 0, 0); }
      PINSTAGE(16, 1);
#pragma unroll
      for (int i = 0; i < 8; ++i) { h16x8 a = __builtin_bit_cast(h16x8, hf[1 * 8 + i]);
        aR[1] = __builtin_amdgcn_mfma_f32_16x16x32_f16(a, wrf[i], aR[1], 0, 0, 0);
        aZ[1] = __builtin_amdgcn_mfma_f32_16x16x32_f16(a, wzf[i], aZ[1], 0, 0, 0);
        aN[1] = __builtin_amdgcn_mfma_f32_16x16x32_f16(a, wnf[i], aN[1], 0, 0, 0); }
      PINSTAGE(8, 2);
#pragma unroll
      for (int i = 0; i < 8; ++i) { h16x8 a = __builtin_bit_cast(h16x8, hf[2 * 8 + i]);
        aR[2] = __builtin_amdgcn_mfma_f32_16x16x32_f16(a, wrf[i], aR[2], 0, 0, 0);
        aZ[2] = __builtin_amdgcn_mfma_f32_16x16x32_f16(a, wzf[i], aZ[2], 0, 0, 0);
        aN[2] = __builtin_amdgcn_mfma_f32_16x16x32_f16(a, wnf[i], aN[2], 0, 0, 0); }
      PINSTAGE(0, 3);
#pragma unroll
      for (int i = 0; i < 8; ++i) { h16x8 a = __builtin_bit_cast(h16x8, hf[3 * 8 + i]);
        aR[3] = __builtin_amdgcn_mfma_f32_16x16x32_f16(a, wrf[i], aR[3], 0, 0, 0);
        aZ[3] = __builtin_amdgcn_mfma_f32_16x16x32_f16(a, wzf[i], aZ[3], 0, 0, 0);
        aN[3] = __builtin_amdgcn_mfma_f32_16x16x32_f16(a, wnf[i], aN[3], 0, 0, 0); }
    }

    // ---- cross-wave K-reduction via LDS ----
#pragma unroll
    for (int b2 = 0; b2 < 4; ++b2)
      if (b2 != w) {
        *(f32x4*)&buf[w][0][b2][lane][0] = aR[b2];
        *(f32x4*)&buf[w][1][b2][lane][0] = aZ[b2];
        *(f32x4*)&buf[w][2][b2][lane][0] = aN[b2];
      }
    __syncthreads();
    f32x4 sR = aR[w], sZ = aZ[w], sN = aN[w];
#pragma unroll
    for (int v = 0; v < 4; ++v)
      if (v != w) {
        sR += *(const f32x4*)&buf[v][0][w][lane][0];
        sZ += *(const f32x4*)&buf[v][1][w][lane][0];
        sN += *(const f32x4*)&buf[v][2][w][lane][0];
      }

    // ---- gate epilogue; fp32 h chain in registers; fp16 h to transpose buffer ----
#pragma unroll
    for (int j = 0; j < 4; ++j) {
      float r = 1.f / (1.f + __expf(-(gr[j] + sR[j])));
      float z = 1.f / (1.f + __expf(-(gz[j] + sZ[j])));
      float np = gn[j] + r * sN[j];
      float e2 = __expf(-2.f * fabsf(np));              // overflow-safe tanh
      float tn = (1.f - e2) / (1.f + e2);
      tn = np < 0.f ? -tn : tn;
      float hnew = (1.f - z) * tn + z * hreg[j];
      hreg[j] = hnew;
      tbuf[(w << 8) + ((((q << 2) + j) | ((dloc >> 3) << 4)) << 3) + (dloc & 7)] = f2h(hnew);
    }
    __syncthreads();

    // ---- coalesced h store: thread tid covers 8 B of this WG's 2 KB region ----
    {
      unsigned long long pv = *(const unsigned long long*)(tbuf + (w << 8) + lane * 4);
      unsigned short* gp = hcur + ((long)(w * 32 + (wg >> 1)) << 9) + ((wg & 1) << 8) + lane * 4;
      asm volatile("global_store_dwordx2 %0, %1, off sc1" :: "v"(gp), "v"(pv) : "memory");
      asm volatile("s_waitcnt vmcnt(0)" ::: "memory");
    }
    __syncthreads();
    if (tid == 0)
      __hip_atomic_store(&flags[wg * FSTRIDE], (unsigned)t, __ATOMIC_RELAXED, __HIP_MEMORY_SCOPE_AGENT);
  }
}

extern "C" void kernel_launch(void* const* d_in, const int* in_sizes, int n_in,
                              void* d_out, int out_size, void* d_ws, size_t ws_size,
                              hipStream_t stream) {
  const int*   y    = (const int*)d_in[0];
  const float* em   = (const float*)d_in[1];
  const float* wih  = (const float*)d_in[2];
  const float* bih  = (const float*)d_in[3];
  const float* whh  = (const float*)d_in[4];
  const float* bhh  = (const float*)d_in[5];
  const float* lw   = (const float*)d_in[6];
  const float* lb   = (const float*)d_in[7];
  const float* init = (const float*)d_in[8];
  float* out = (float*)d_out;

  char* ws = (char*)d_ws;
  size_t off = 0;
  auto alloc = [&](size_t n) { void* p = ws + off; off += (n + 255) & ~(size_t)255; return p; };
  unsigned short* wh_sw   = (unsigned short*)alloc(6291456);    // W_hh fp16 swizzled
  unsigned short* wi_sw   = (unsigned short*)alloc(6291456);    // W_ih fp16 swizzled
  unsigned short* em_sw   = (unsigned short*)alloc(2097152);    // embed fp16 swizzled
  unsigned short* lw_sw   = (unsigned short*)alloc(2097152);    // linear_w fp16 swizzled
  float*          gtab    = (float*)alloc(12582912);            // [V,3072] token gate table
  float*          bias_sum= (float*)alloc(12288);               // bias_ih + bias_hh
  unsigned int*   flags   = (unsigned int*)alloc(8192);         // 64 flags, 128-B spread
  unsigned short* hs      = (unsigned short*)alloc(67371008UL); // 514 h slots, fp16 swizzled
  (void)ws_size; (void)in_sizes; (void)n_in; (void)out_size;

  predictor_prep<<<dim3(33044), dim3(256), 0, stream>>>(
      whh, wih, em, lw, bih, bhh, init, wh_sw, wi_sw, em_sw, lw_sw, bias_sum, hs, flags);
  predictor_gemm<<<dim3(48, 16), dim3(256), 0, stream>>>(
      em_sw, 65536L, wi_sw, bias_sum, gtab, /*rowmul_i=*/1, /*rowmul_c=*/64, /*stride=*/3072);
  predictor_rnn<<<dim3(NWG), dim3(256), 0, stream>>>(wh_sw, gtab, y, init, hs, flags);
  predictor_gemm<<<dim3(16, 513), dim3(256), 0, stream>>>(
      hs + 65536, 65536L, lw_sw, lb, out, /*rowmul_i=*/513, /*rowmul_c=*/1, /*stride=*/1024);
}